// Round 12
// baseline (42.334 us; speedup 1.0000x reference)
//
#include <hip/hip_runtime.h>
#include <cstdint>

typedef unsigned short ushort_t;
typedef unsigned int u32;
typedef unsigned long long u64;
typedef __attribute__((ext_vector_type(8))) short bf16x8;
typedef __attribute__((ext_vector_type(16))) float f32x16;

#define N_PRED 8192
#define N_GT   32768

// wave = 128 preds (4 B-frags of 32) x 512 targets (16 A-tiles of 32)
// NN: 64 pred-groups x 64 splits = 4096 waves; REP: 64 x 16 = 1024
#define NN_WAVES  4096
#define ALL_WAVES 5120

// ws: gtA 1MB | prA 256K | prB 256K | keysNN u64[64][8192] 4MB | keysRP u64[16][8192] 1MB | partials
#define O_PRA  1048576u
#define O_PRB  1310720u
#define O_KNN  1572864u
#define O_KRP  5767168u
#define O_PART 6815744u

__device__ __forceinline__ float max3f(float a, float b, float c) {
    float d;
    asm("v_max3_f32 %0, %1, %2, %3" : "=v"(d) : "v"(a), "v"(b), "v"(c));
    return d;
}
__device__ __forceinline__ ushort_t f2b(float v) {   // round-to-nearest-even bf16
    u32 b = __float_as_uint(v);
    return (ushort_t)((b + 0x7FFFu + ((b >> 16) & 1u)) >> 16);
}
__device__ __forceinline__ u32 packf(float v) {      // monotone float->u32
    const u32 b = __float_as_uint(v);
    return b ^ ((u32)((int)b >> 31) | 0x80000000u);
}

// fold 16 accs -> max, latch tile index T on strict improvement (first wins ties)
#define LATCH(ACC, B, K, T)                                        \
    {                                                              \
        const float _m0 = max3f(ACC[0], ACC[1], ACC[2]);           \
        const float _m1 = max3f(ACC[3], ACC[4], ACC[5]);           \
        const float _m2 = max3f(ACC[6], ACC[7], ACC[8]);           \
        const float _m3 = max3f(ACC[9], ACC[10], ACC[11]);         \
        const float _m4 = max3f(ACC[12], ACC[13], ACC[14]);        \
        const float _m5 = max3f(_m0, _m1, ACC[15]);                \
        const float _m6 = max3f(_m2, _m3, _m4);                    \
        const float _gm = fmaxf(_m5, _m6);                         \
        K = (_gm > B) ? (u32)(T) : K;                              \
        B = fmaxf(B, _gm);                                         \
    }

// mask the self element (C/D: col=lane&31, row=(r&3)+8*(r>>2)+4*(lane>>5))
#define MASKROW(ACC)                                               \
    {                                                              \
        _Pragma("unroll")                                          \
        for (int _r = 0; _r < 16; ++_r) {                          \
            const int _row = (_r & 3) + 8 * (_r >> 2) + rowoff;    \
            ACC[_r] = (_row == col) ? -3.0e38f : ACC[_r];          \
        }                                                          \
    }

// ---- prep: pack bf16 hi/lo fragments, 32-row groups (row=lane&31, k-half=lane>>5)
// A (target): k0-7=[xh,yh,zh,xh,yh,zh,xl,yl]  k8-15=[zl,wh,wl,0...]  (w=-0.5|g|^2)
// B (query) : k0-7=[xh,yh,zh,xl,yl,zl,xh,yh]  k8-15=[zh,1,1,0...]
__global__ __launch_bounds__(256) void k_prep(const float* __restrict__ pred,
                                              const float* __restrict__ gt,
                                              ushort_t* __restrict__ gtA,
                                              ushort_t* __restrict__ prA,
                                              ushort_t* __restrict__ prB) {
    const int i = blockIdx.x * 256 + threadIdx.x;
    if (i < N_GT) {
        const float x = gt[i * 6 + 0], y = gt[i * 6 + 1], z = gt[i * 6 + 2];
        const ushort_t xh = f2b(x), yh = f2b(y), zh = f2b(z);
        const ushort_t xl = f2b(x - __uint_as_float((u32)xh << 16));
        const ushort_t yl = f2b(y - __uint_as_float((u32)yh << 16));
        const ushort_t zl = f2b(z - __uint_as_float((u32)zh << 16));
        const float w = -0.5f * fmaf(z, z, fmaf(y, y, x * x));
        const ushort_t wh = f2b(w);
        const ushort_t wl = f2b(w - __uint_as_float((u32)wh << 16));
        ushort_t* d = gtA + (i >> 5) * 512 + (i & 31) * 8;
        d[0] = xh; d[1] = yh; d[2] = zh; d[3] = xh; d[4] = yh; d[5] = zh; d[6] = xl; d[7] = yl;
        d += 256;
        d[0] = zl; d[1] = wh; d[2] = wl; d[3] = 0; d[4] = 0; d[5] = 0; d[6] = 0; d[7] = 0;
    }
    if (i < N_PRED) {
        const float x = pred[i * 6 + 0], y = pred[i * 6 + 1], z = pred[i * 6 + 2];
        const ushort_t xh = f2b(x), yh = f2b(y), zh = f2b(z);
        const ushort_t xl = f2b(x - __uint_as_float((u32)xh << 16));
        const ushort_t yl = f2b(y - __uint_as_float((u32)yh << 16));
        const ushort_t zl = f2b(z - __uint_as_float((u32)zh << 16));
        const float w = -0.5f * fmaf(z, z, fmaf(y, y, x * x));
        const ushort_t wh = f2b(w);
        const ushort_t wl = f2b(w - __uint_as_float((u32)wh << 16));
        ushort_t* a = prA + (i >> 5) * 512 + (i & 31) * 8;
        a[0] = xh; a[1] = yh; a[2] = zh; a[3] = xh; a[4] = yh; a[5] = zh; a[6] = xl; a[7] = yl;
        a += 256;
        a[0] = zl; a[1] = wh; a[2] = wl; a[3] = 0; a[4] = 0; a[5] = 0; a[6] = 0; a[7] = 0;
        const ushort_t ONE = 0x3F80;
        ushort_t* b = prB + (i >> 5) * 512 + (i & 31) * 8;
        b[0] = xh; b[1] = yh; b[2] = zh; b[3] = xl; b[4] = yl; b[5] = zl; b[6] = xh; b[7] = yh;
        b += 256;
        b[0] = zh; b[1] = ONE; b[2] = ONE; b[3] = 0; b[4] = 0; b[5] = 0; b[6] = 0; b[7] = 0;
    }
}

// ---- scan loop: 16 A-tiles, 2-deep prefetch, per-tile argmax latch ----
template <bool DIAG>
__device__ __forceinline__ void scan16(const bf16x8* __restrict__ ap,
                                       const bf16x8 B0, const bf16x8 B1,
                                       const bf16x8 B2, const bf16x8 B3,
                                       const int ts0, const int ts1,
                                       const int ts2, const int ts3,
                                       const int col, const int rowoff,
                                       float& b0, float& b1, float& b2, float& b3,
                                       u32& k0, u32& k1, u32& k2, u32& k3) {
    const f32x16 zc = {};
    bf16x8 Aa = ap[0];
    bf16x8 Ab = ap[64];
#pragma unroll
    for (int t = 0; t < 16; ++t) {
        const int tn = (t + 2 < 16) ? t + 2 : 15;
        const bf16x8 An = ap[tn * 64];
        f32x16 accA = __builtin_amdgcn_mfma_f32_32x32x16_bf16(Aa, B0, zc, 0, 0, 0);
        f32x16 accB = __builtin_amdgcn_mfma_f32_32x32x16_bf16(Aa, B1, zc, 0, 0, 0);
        if (DIAG && t == ts0) MASKROW(accA);
        LATCH(accA, b0, k0, t);
        accA = __builtin_amdgcn_mfma_f32_32x32x16_bf16(Aa, B2, zc, 0, 0, 0);
        if (DIAG && t == ts1) MASKROW(accB);
        LATCH(accB, b1, k1, t);
        accB = __builtin_amdgcn_mfma_f32_32x32x16_bf16(Aa, B3, zc, 0, 0, 0);
        if (DIAG && t == ts2) MASKROW(accA);
        LATCH(accA, b2, k2, t);
        if (DIAG && t == ts3) MASKROW(accB);
        LATCH(accB, b3, k3, t);
        Aa = Ab;
        Ab = An;
    }
}

// ---- pair: 32x32x16 MFMA bulk argmax at 32-point tile granularity ----
__global__ __launch_bounds__(256) void k_pair(const ushort_t* __restrict__ gtA,
                                              const ushort_t* __restrict__ prA,
                                              const ushort_t* __restrict__ prB,
                                              u64* __restrict__ keysNN,
                                              u64* __restrict__ keysRP) {
    const int wid = blockIdx.x * 4 + (threadIdx.x >> 6);
    const int lane = threadIdx.x & 63;

    const bool isNN = (wid < NN_WAVES);
    const int rw = isNN ? wid : (wid - NN_WAVES);
    const int pg = rw & 63;            // pred group of 128
    const int sp = rw >> 6;            // target split of 512

    const int lu = (lane >> 5) * 32 + (lane & 31);
    const int col = lane & 31;
    const int rowoff = (lane >> 5) * 4;

    const bf16x8* bp = (const bf16x8*)prB;
    const bf16x8 B0 = bp[(pg * 4 + 0) * 64 + lu];
    const bf16x8 B1 = bp[(pg * 4 + 1) * 64 + lu];
    const bf16x8 B2 = bp[(pg * 4 + 2) * 64 + lu];
    const bf16x8 B3 = bp[(pg * 4 + 3) * 64 + lu];

    const bf16x8* ap = (const bf16x8*)(isNN ? gtA : prA) + sp * 1024 + lu;

    float b0 = -3.0e38f, b1 = -3.0e38f, b2 = -3.0e38f, b3 = -3.0e38f;
    u32 k0 = 0, k1 = 0, k2 = 0, k3 = 0;

    const bool diag = (!isNN) && (sp == (pg >> 2));
    if (diag) {
        const int tb = (pg & 3) * 4;
        scan16<true>(ap, B0, B1, B2, B3, tb, tb + 1, tb + 2, tb + 3,
                     col, rowoff, b0, b1, b2, b3, k0, k1, k2, k3);
    } else {
        scan16<false>(ap, B0, B1, B2, B3, -1, -1, -1, -1,
                      col, rowoff, b0, b1, b2, b3, k0, k1, k2, k3);
    }

    // merge the two row-halves (lane, lane^32 share a pred col); tie -> smaller tile
#define FOLD(B, K)                                                  \
    {                                                               \
        const float _ob = __shfl_xor(B, 32);                        \
        const u32 _ok = __shfl_xor(K, 32);                          \
        const bool _tk = (_ob > B) || (_ob == B && _ok < K);        \
        B = _tk ? _ob : B;                                          \
        K = _tk ? _ok : K;                                          \
    }
    FOLD(b0, k0); FOLD(b1, k1); FOLD(b2, k2); FOLD(b3, k3);
#undef FOLD

    if (lane < 32) {
        u64* keys = isNN ? keysNN : keysRP;
        const int Pb = pg * 128 + col;
        const u32 tb = (u32)(sp * 16);
        keys[(size_t)sp * N_PRED + Pb +  0] = ((u64)packf(b0) << 32) | (u64)(~(tb + k0));
        keys[(size_t)sp * N_PRED + Pb + 32] = ((u64)packf(b1) << 32) | (u64)(~(tb + k1));
        keys[(size_t)sp * N_PRED + Pb + 64] = ((u64)packf(b2) << 32) | (u64)(~(tb + k2));
        keys[(size_t)sp * N_PRED + Pb + 96] = ((u64)packf(b3) << 32) | (u64)(~(tb + k3));
    }
}

// ---- finalize: wave-per-pred; u64 key reduce; 32-point exact rescans; losses ----
__global__ __launch_bounds__(256) void k_fin(const float* __restrict__ pred,
                                             const float* __restrict__ gt,
                                             const u64* __restrict__ keysNN,
                                             const u64* __restrict__ keysRP,
                                             float* __restrict__ partials) {
    const int wave = threadIdx.x >> 6;
    const int lane = threadIdx.x & 63;
    const int p = blockIdx.x * 4 + wave;

    const float px = pred[p * 6 + 0], py = pred[p * 6 + 1], pz = pred[p * 6 + 2];

    // --- NN: reduce 64 split keys (u64 max: bigger h, then smaller tile) ---
    u64 kv = keysNN[(size_t)lane * N_PRED + p];
#pragma unroll
    for (int off = 32; off > 0; off >>= 1) {
        const u64 o = __shfl_xor(kv, off);
        kv = (o > kv) ? o : kv;
    }
    const u32 tile = ~((u32)kv);
    // exact fp32 rescan of the 32-point tile (ties -> smallest gt index)
    {
    }
    const int g = (int)tile * 32 + (lane & 31);
    float bh;
    int bj;
    {
        const float x = gt[g * 6 + 0], y = gt[g * 6 + 1], z = gt[g * 6 + 2];
        const float w = -0.5f * fmaf(z, z, fmaf(y, y, x * x));
        bh = fmaf(px, x, fmaf(py, y, fmaf(pz, z, w)));
        bj = g;
    }
#pragma unroll
    for (int off = 32; off > 0; off >>= 1) {
        const float oh = __shfl_xor(bh, off);
        const int og = __shfl_xor(bj, off);
        const bool take = (oh > bh) || (oh == bh && og < bj);
        bh = take ? oh : bh;
        bj = take ? og : bj;
    }
    const int j = bj;

    // --- REP: reduce 16 split keys (self-free), exact rescan of tile ---
    u64 rv = (lane < 16) ? keysRP[(size_t)lane * N_PRED + p] : 0ull;
#pragma unroll
    for (int off = 32; off > 0; off >>= 1) {
        const u64 o = __shfl_xor(rv, off);
        rv = (o > rv) ? o : rv;
    }
    const u32 tile2 = ~((u32)rv);
    const int q = (int)tile2 * 32 + (lane & 31);
    float hr;
    {
        const float x = pred[q * 6 + 0], y = pred[q * 6 + 1], z = pred[q * 6 + 2];
        const float w = -0.5f * fmaf(z, z, fmaf(y, y, x * x));
        float h = fmaf(px, x, fmaf(py, y, fmaf(pz, z, w)));
        hr = (q == p) ? -3.0e38f : h;
    }
#pragma unroll
    for (int off = 32; off > 0; off >>= 1) hr = fmaxf(hr, __shfl_xor(hr, off));

    __shared__ float red[4][3];
    if (lane == 0) {
        const float gx = gt[j * 6 + 0], gy = gt[j * 6 + 1], gz = gt[j * 6 + 2];
        const float dx = px - gx, dy = py - gy, dz = pz - gz;
        const float att = dx * dx + dy * dy + dz * dz;

        const float pnx = pred[p * 6 + 3], pny = pred[p * 6 + 4], pnz = pred[p * 6 + 5];
        const float gnx = gt[j * 6 + 3],   gny = gt[j * 6 + 4],   gnz = gt[j * 6 + 5];
        const float pl = fmaxf(sqrtf(pnx * pnx + pny * pny + pnz * pnz), 1e-5f);
        const float gl = fmaxf(sqrtf(gnx * gnx + gny * gny + gnz * gnz), 1e-5f);
        const float nrm = 1.0f - (pnx * gnx + pny * gny + pnz * gnz) / (pl * gl);

        const float pp2 = px * px + py * py + pz * pz;
        float d2 = fmaf(-2.0f, hr, pp2);
        d2 = fmaxf(d2, 0.0f);
        const float xa = 100.0f * (0.3f - sqrtf(d2));
        const float sp2 = fmaxf(xa, 0.0f) + log1pf(expf(-fabsf(xa)));

        red[wave][0] = att;
        red[wave][1] = nrm;
        red[wave][2] = sp2 * sp2;
    }
    __syncthreads();
    if (threadIdx.x < 3)
        partials[blockIdx.x * 3 + threadIdx.x] =
            red[0][threadIdx.x] + red[1][threadIdx.x] +
            red[2][threadIdx.x] + red[3][threadIdx.x];
}

__device__ __forceinline__ float wave_reduce(float v) {
#pragma unroll
    for (int off = 32; off > 0; off >>= 1) v += __shfl_down(v, off, 64);
    return v;
}

__global__ __launch_bounds__(256) void k_comb(const float* __restrict__ partials,
                                              float* __restrict__ out) {
    float a = 0.f, n = 0.f, r = 0.f;
    const int t = threadIdx.x;
#pragma unroll
    for (int k = 0; k < 8; ++k) {
        const int row = t + k * 256;          // 2048 rows
        a += partials[row * 3 + 0];
        n += partials[row * 3 + 1];
        r += partials[row * 3 + 2];
    }
    a = wave_reduce(a);
    n = wave_reduce(n);
    r = wave_reduce(r);
    __shared__ float red[3][4];
    const int wave = t >> 6, lane = t & 63;
    if (lane == 0) { red[0][wave] = a; red[1][wave] = n; red[2][wave] = r; }
    __syncthreads();
    if (t == 0) {
        const float A = red[0][0] + red[0][1] + red[0][2] + red[0][3];
        const float Nn = red[1][0] + red[1][1] + red[1][2] + red[1][3];
        const float R = red[2][0] + red[2][1] + red[2][2] + red[2][3];
        out[0] = A / (float)(N_PRED * 3) + R / (float)N_PRED + 10.0f * (Nn / (float)N_PRED);
    }
}

extern "C" void kernel_launch(void* const* d_in, const int* in_sizes, int n_in,
                              void* d_out, int out_size, void* d_ws, size_t ws_size,
                              hipStream_t stream) {
    const float* pred = (const float*)d_in[0];   // (8192, 6)
    const float* gt   = (const float*)d_in[3];   // (32768, 6)
    float* out = (float*)d_out;
    char* ws = (char*)d_ws;

    ushort_t* gtA = (ushort_t*)ws;
    ushort_t* prA = (ushort_t*)(ws + O_PRA);
    ushort_t* prB = (ushort_t*)(ws + O_PRB);
    u64* keysNN = (u64*)(ws + O_KNN);
    u64* keysRP = (u64*)(ws + O_KRP);
    float* partials = (float*)(ws + O_PART);

    k_prep<<<N_GT / 256, 256, 0, stream>>>(pred, gt, gtA, prA, prB);
    k_pair<<<ALL_WAVES / 4, 256, 0, stream>>>(gtA, prA, prB, keysNN, keysRP);
    k_fin<<<N_PRED / 4, 256, 0, stream>>>(pred, gt, keysNN, keysRP, partials);
    k_comb<<<1, 256, 0, stream>>>(partials, out);
}

// Round 13
// 39.589 us; speedup vs baseline: 1.0693x; 1.0693x over previous
//
#include <hip/hip_runtime.h>
#include <cstdint>

typedef unsigned short ushort_t;
typedef unsigned int u32;
typedef unsigned long long u64;
typedef __attribute__((ext_vector_type(8))) short bf16x8;
typedef __attribute__((ext_vector_type(16))) float f32x16;

#define N_PRED 8192
#define N_GT   32768

// wave = 128 preds (4 B-frags of 32) x 512 targets (16 A-tiles of 32)
// NN: 64 pred-groups x 64 splits = 4096 waves; REP: 64 x 16 = 1024
#define NN_WAVES  4096
#define ALL_WAVES 5120

// ws: gtA 1MB | prA 256K | prB 256K | keysNN u64[64][8192] 4MB | keysRP u64[16][8192] 1MB | partials
#define O_PRA  1048576u
#define O_PRB  1310720u
#define O_KNN  1572864u
#define O_KRP  5767168u
#define O_PART 6815744u

__device__ __forceinline__ float max3f(float a, float b, float c) {
    float d;
    asm("v_max3_f32 %0, %1, %2, %3" : "=v"(d) : "v"(a), "v"(b), "v"(c));
    return d;
}
__device__ __forceinline__ ushort_t f2b(float v) {   // round-to-nearest-even bf16
    u32 b = __float_as_uint(v);
    return (ushort_t)((b + 0x7FFFu + ((b >> 16) & 1u)) >> 16);
}
__device__ __forceinline__ u32 packf(float v) {      // monotone float->u32
    const u32 b = __float_as_uint(v);
    return b ^ ((u32)((int)b >> 31) | 0x80000000u);
}
// fold 16 accs into running max (8 x v_max3 + 1 fmax) -- r11's lean reduction
__device__ __forceinline__ float red16(const f32x16 a, float best) {
    const float m0 = max3f(a[0], a[1], a[2]);
    const float m1 = max3f(a[3], a[4], a[5]);
    const float m2 = max3f(a[6], a[7], a[8]);
    const float m3 = max3f(a[9], a[10], a[11]);
    const float m4 = max3f(a[12], a[13], a[14]);
    const float m5 = max3f(m0, m1, a[15]);
    const float m6 = max3f(m2, m3, m4);
    return max3f(best, m5, m6);
}

// mask the self element (C/D: col=lane&31, row=(r&3)+8*(r>>2)+4*(lane>>5))
#define MASKROW(ACC)                                               \
    {                                                              \
        _Pragma("unroll")                                          \
        for (int _r = 0; _r < 16; ++_r) {                          \
            const int _row = (_r & 3) + 8 * (_r >> 2) + rowoff;    \
            ACC[_r] = (_row == col) ? -3.0e38f : ACC[_r];          \
        }                                                          \
    }

// ---- prep: pack bf16 hi/lo fragments, 32-row groups (row=lane&31, k-half=lane>>5)
// A (target): k0-7=[xh,yh,zh,xh,yh,zh,xl,yl]  k8-15=[zl,wh,wl,0...]  (w=-0.5|g|^2)
// B (query) : k0-7=[xh,yh,zh,xl,yl,zl,xh,yh]  k8-15=[zh,1,1,0...]
__global__ __launch_bounds__(256) void k_prep(const float* __restrict__ pred,
                                              const float* __restrict__ gt,
                                              ushort_t* __restrict__ gtA,
                                              ushort_t* __restrict__ prA,
                                              ushort_t* __restrict__ prB) {
    const int i = blockIdx.x * 256 + threadIdx.x;
    if (i < N_GT) {
        const float x = gt[i * 6 + 0], y = gt[i * 6 + 1], z = gt[i * 6 + 2];
        const ushort_t xh = f2b(x), yh = f2b(y), zh = f2b(z);
        const ushort_t xl = f2b(x - __uint_as_float((u32)xh << 16));
        const ushort_t yl = f2b(y - __uint_as_float((u32)yh << 16));
        const ushort_t zl = f2b(z - __uint_as_float((u32)zh << 16));
        const float w = -0.5f * fmaf(z, z, fmaf(y, y, x * x));
        const ushort_t wh = f2b(w);
        const ushort_t wl = f2b(w - __uint_as_float((u32)wh << 16));
        ushort_t* d = gtA + (i >> 5) * 512 + (i & 31) * 8;
        d[0] = xh; d[1] = yh; d[2] = zh; d[3] = xh; d[4] = yh; d[5] = zh; d[6] = xl; d[7] = yl;
        d += 256;
        d[0] = zl; d[1] = wh; d[2] = wl; d[3] = 0; d[4] = 0; d[5] = 0; d[6] = 0; d[7] = 0;
    }
    if (i < N_PRED) {
        const float x = pred[i * 6 + 0], y = pred[i * 6 + 1], z = pred[i * 6 + 2];
        const ushort_t xh = f2b(x), yh = f2b(y), zh = f2b(z);
        const ushort_t xl = f2b(x - __uint_as_float((u32)xh << 16));
        const ushort_t yl = f2b(y - __uint_as_float((u32)yh << 16));
        const ushort_t zl = f2b(z - __uint_as_float((u32)zh << 16));
        const float w = -0.5f * fmaf(z, z, fmaf(y, y, x * x));
        const ushort_t wh = f2b(w);
        const ushort_t wl = f2b(w - __uint_as_float((u32)wh << 16));
        ushort_t* a = prA + (i >> 5) * 512 + (i & 31) * 8;
        a[0] = xh; a[1] = yh; a[2] = zh; a[3] = xh; a[4] = yh; a[5] = zh; a[6] = xl; a[7] = yl;
        a += 256;
        a[0] = zl; a[1] = wh; a[2] = wl; a[3] = 0; a[4] = 0; a[5] = 0; a[6] = 0; a[7] = 0;
        const ushort_t ONE = 0x3F80;
        ushort_t* b = prB + (i >> 5) * 512 + (i & 31) * 8;
        b[0] = xh; b[1] = yh; b[2] = zh; b[3] = xl; b[4] = yl; b[5] = zl; b[6] = xh; b[7] = yh;
        b += 256;
        b[0] = zh; b[1] = ONE; b[2] = ONE; b[3] = 0; b[4] = 0; b[5] = 0; b[6] = 0; b[7] = 0;
    }
}

// ---- scan: 16 A-tiles, r11-lean body, argmax latched per 4-tile group ----
template <bool DIAG>
__device__ __forceinline__ void scan16(const bf16x8* __restrict__ ap,
                                       const bf16x8 B0, const bf16x8 B1,
                                       const bf16x8 B2, const bf16x8 B3,
                                       const int ts0, const int ts1,
                                       const int ts2, const int ts3,
                                       const int col, const int rowoff,
                                       float& b0, float& b1, float& b2, float& b3,
                                       u32& k0, u32& k1, u32& k2, u32& k3) {
    const f32x16 zc = {};
    bf16x8 Acur = ap[0];
#pragma unroll
    for (int G = 0; G < 4; ++G) {
        float g0 = -3.0e38f, g1 = -3.0e38f, g2 = -3.0e38f, g3 = -3.0e38f;
#pragma unroll
        for (int tt = 0; tt < 4; ++tt) {
            const int t = G * 4 + tt;
            const bf16x8 Anxt = (t < 15) ? ap[(t + 1) * 64] : Acur;
            f32x16 accA = __builtin_amdgcn_mfma_f32_32x32x16_bf16(Acur, B0, zc, 0, 0, 0);
            f32x16 accB = __builtin_amdgcn_mfma_f32_32x32x16_bf16(Acur, B1, zc, 0, 0, 0);
            if (DIAG && t == ts0) MASKROW(accA);
            g0 = red16(accA, g0);
            accA = __builtin_amdgcn_mfma_f32_32x32x16_bf16(Acur, B2, zc, 0, 0, 0);
            if (DIAG && t == ts1) MASKROW(accB);
            g1 = red16(accB, g1);
            accB = __builtin_amdgcn_mfma_f32_32x32x16_bf16(Acur, B3, zc, 0, 0, 0);
            if (DIAG && t == ts2) MASKROW(accA);
            g2 = red16(accA, g2);
            if (DIAG && t == ts3) MASKROW(accB);
            g3 = red16(accB, g3);
            Acur = Anxt;
        }
        k0 = (g0 > b0) ? (u32)G : k0;  b0 = fmaxf(b0, g0);
        k1 = (g1 > b1) ? (u32)G : k1;  b1 = fmaxf(b1, g1);
        k2 = (g2 > b2) ? (u32)G : k2;  b2 = fmaxf(b2, g2);
        k3 = (g3 > b3) ? (u32)G : k3;  b3 = fmaxf(b3, g3);
    }
}

// ---- pair: 32x32x16 MFMA bulk argmax at 128-point group granularity ----
__global__ __launch_bounds__(256) void k_pair(const ushort_t* __restrict__ gtA,
                                              const ushort_t* __restrict__ prA,
                                              const ushort_t* __restrict__ prB,
                                              u64* __restrict__ keysNN,
                                              u64* __restrict__ keysRP) {
    const int wid = blockIdx.x * 4 + (threadIdx.x >> 6);
    const int lane = threadIdx.x & 63;

    const bool isNN = (wid < NN_WAVES);
    const int rw = isNN ? wid : (wid - NN_WAVES);
    const int pg = rw & 63;            // pred group of 128
    const int sp = rw >> 6;            // target split of 512

    const int col = lane & 31;
    const int rowoff = (lane >> 5) * 4;

    const bf16x8* bp = (const bf16x8*)prB;
    const bf16x8 B0 = bp[(pg * 4 + 0) * 64 + lane];
    const bf16x8 B1 = bp[(pg * 4 + 1) * 64 + lane];
    const bf16x8 B2 = bp[(pg * 4 + 2) * 64 + lane];
    const bf16x8 B3 = bp[(pg * 4 + 3) * 64 + lane];

    const bf16x8* ap = (const bf16x8*)(isNN ? gtA : prA) + sp * 1024 + lane;

    float b0 = -3.0e38f, b1 = -3.0e38f, b2 = -3.0e38f, b3 = -3.0e38f;
    u32 k0 = 0, k1 = 0, k2 = 0, k3 = 0;

    const bool diag = (!isNN) && (sp == (pg >> 2));
    if (diag) {
        const int tb = (pg & 3) * 4;
        scan16<true>(ap, B0, B1, B2, B3, tb, tb + 1, tb + 2, tb + 3,
                     col, rowoff, b0, b1, b2, b3, k0, k1, k2, k3);
    } else {
        scan16<false>(ap, B0, B1, B2, B3, -1, -1, -1, -1,
                      col, rowoff, b0, b1, b2, b3, k0, k1, k2, k3);
    }

    // merge the two row-halves (lane, lane^32 share a pred col); tie -> smaller group
#define FOLD(B, K)                                                  \
    {                                                               \
        const float _ob = __shfl_xor(B, 32);                        \
        const u32 _ok = __shfl_xor(K, 32);                          \
        const bool _tk = (_ob > B) || (_ob == B && _ok < K);        \
        B = _tk ? _ob : B;                                          \
        K = _tk ? _ok : K;                                          \
    }
    FOLD(b0, k0); FOLD(b1, k1); FOLD(b2, k2); FOLD(b3, k3);
#undef FOLD

    if (lane < 32) {
        u64* keys = isNN ? keysNN : keysRP;
        const int Pb = pg * 128 + col;
        const u32 gb = (u32)(sp * 4);
        keys[(size_t)sp * N_PRED + Pb +  0] = ((u64)packf(b0) << 32) | (u64)(~(gb + k0));
        keys[(size_t)sp * N_PRED + Pb + 32] = ((u64)packf(b1) << 32) | (u64)(~(gb + k1));
        keys[(size_t)sp * N_PRED + Pb + 64] = ((u64)packf(b2) << 32) | (u64)(~(gb + k2));
        keys[(size_t)sp * N_PRED + Pb + 96] = ((u64)packf(b3) << 32) | (u64)(~(gb + k3));
    }
}

// ---- finalize: wave-per-pred; key reduce; 128-point exact rescans; losses ----
__global__ __launch_bounds__(256) void k_fin(const float* __restrict__ pred,
                                             const float* __restrict__ gt,
                                             const u64* __restrict__ keysNN,
                                             const u64* __restrict__ keysRP,
                                             float* __restrict__ partials) {
    const int wave = threadIdx.x >> 6;
    const int lane = threadIdx.x & 63;
    const int p = blockIdx.x * 4 + wave;

    const float px = pred[p * 6 + 0], py = pred[p * 6 + 1], pz = pred[p * 6 + 2];

    // --- NN: reduce 64 split keys (bigger h, then smaller group) ---
    u64 kv = keysNN[(size_t)lane * N_PRED + p];
#pragma unroll
    for (int off = 32; off > 0; off >>= 1) {
        const u64 o = __shfl_xor(kv, off);
        kv = (o > kv) ? o : kv;
    }
    const int G = (int)(~(u32)kv);          // group of 128 gt
    // exact fp32 rescan (ascending i -> numpy first-max tie semantics)
    float bh = -3.0e38f;
    int bj = 0x7FFFFFFF;
#pragma unroll
    for (int i = 0; i < 2; ++i) {
        const int g = G * 128 + i * 64 + lane;
        const float x = gt[g * 6 + 0], y = gt[g * 6 + 1], z = gt[g * 6 + 2];
        const float w = -0.5f * fmaf(z, z, fmaf(y, y, x * x));
        const float h = fmaf(px, x, fmaf(py, y, fmaf(pz, z, w)));
        if (h > bh) { bh = h; bj = g; }
    }
#pragma unroll
    for (int off = 32; off > 0; off >>= 1) {
        const float oh = __shfl_xor(bh, off);
        const int og = __shfl_xor(bj, off);
        const bool take = (oh > bh) || (oh == bh && og < bj);
        bh = take ? oh : bh;
        bj = take ? og : bj;
    }
    const int j = bj;

    // --- REP: reduce 16 self-free split keys, exact 128-point rescan ---
    u64 rv = (lane < 16) ? keysRP[(size_t)lane * N_PRED + p] : 0ull;
#pragma unroll
    for (int off = 32; off > 0; off >>= 1) {
        const u64 o = __shfl_xor(rv, off);
        rv = (o > rv) ? o : rv;
    }
    const int G2 = (int)(~(u32)rv);         // group of 128 pred
    float hr = -3.0e38f;
#pragma unroll
    for (int i = 0; i < 2; ++i) {
        const int q = G2 * 128 + i * 64 + lane;
        const float x = pred[q * 6 + 0], y = pred[q * 6 + 1], z = pred[q * 6 + 2];
        const float w = -0.5f * fmaf(z, z, fmaf(y, y, x * x));
        float h = fmaf(px, x, fmaf(py, y, fmaf(pz, z, w)));
        h = (q == p) ? -3.0e38f : h;
        hr = fmaxf(hr, h);
    }
#pragma unroll
    for (int off = 32; off > 0; off >>= 1) hr = fmaxf(hr, __shfl_xor(hr, off));

    __shared__ float red[4][3];
    if (lane == 0) {
        const float gx = gt[j * 6 + 0], gy = gt[j * 6 + 1], gz = gt[j * 6 + 2];
        const float dx = px - gx, dy = py - gy, dz = pz - gz;
        const float att = dx * dx + dy * dy + dz * dz;

        const float pnx = pred[p * 6 + 3], pny = pred[p * 6 + 4], pnz = pred[p * 6 + 5];
        const float gnx = gt[j * 6 + 3],   gny = gt[j * 6 + 4],   gnz = gt[j * 6 + 5];
        const float pl = fmaxf(sqrtf(pnx * pnx + pny * pny + pnz * pnz), 1e-5f);
        const float gl = fmaxf(sqrtf(gnx * gnx + gny * gny + gnz * gnz), 1e-5f);
        const float nrm = 1.0f - (pnx * gnx + pny * gny + pnz * gnz) / (pl * gl);

        const float pp2 = px * px + py * py + pz * pz;
        float d2 = fmaf(-2.0f, hr, pp2);
        d2 = fmaxf(d2, 0.0f);
        const float xa = 100.0f * (0.3f - sqrtf(d2));
        const float sp2 = fmaxf(xa, 0.0f) + log1pf(expf(-fabsf(xa)));

        red[wave][0] = att;
        red[wave][1] = nrm;
        red[wave][2] = sp2 * sp2;
    }
    __syncthreads();
    if (threadIdx.x < 3)
        partials[blockIdx.x * 3 + threadIdx.x] =
            red[0][threadIdx.x] + red[1][threadIdx.x] +
            red[2][threadIdx.x] + red[3][threadIdx.x];
}

__device__ __forceinline__ float wave_reduce(float v) {
#pragma unroll
    for (int off = 32; off > 0; off >>= 1) v += __shfl_down(v, off, 64);
    return v;
}

__global__ __launch_bounds__(256) void k_comb(const float* __restrict__ partials,
                                              float* __restrict__ out) {
    float a = 0.f, n = 0.f, r = 0.f;
    const int t = threadIdx.x;
#pragma unroll
    for (int k = 0; k < 8; ++k) {
        const int row = t + k * 256;          // 2048 rows
        a += partials[row * 3 + 0];
        n += partials[row * 3 + 1];
        r += partials[row * 3 + 2];
    }
    a = wave_reduce(a);
    n = wave_reduce(n);
    r = wave_reduce(r);
    __shared__ float red[3][4];
    const int wave = t >> 6, lane = t & 63;
    if (lane == 0) { red[0][wave] = a; red[1][wave] = n; red[2][wave] = r; }
    __syncthreads();
    if (t == 0) {
        const float A = red[0][0] + red[0][1] + red[0][2] + red[0][3];
        const float Nn = red[1][0] + red[1][1] + red[1][2] + red[1][3];
        const float R = red[2][0] + red[2][1] + red[2][2] + red[2][3];
        out[0] = A / (float)(N_PRED * 3) + R / (float)N_PRED + 10.0f * (Nn / (float)N_PRED);
    }
}

extern "C" void kernel_launch(void* const* d_in, const int* in_sizes, int n_in,
                              void* d_out, int out_size, void* d_ws, size_t ws_size,
                              hipStream_t stream) {
    const float* pred = (const float*)d_in[0];   // (8192, 6)
    const float* gt   = (const float*)d_in[3];   // (32768, 6)
    float* out = (float*)d_out;
    char* ws = (char*)d_ws;

    ushort_t* gtA = (ushort_t*)ws;
    ushort_t* prA = (ushort_t*)(ws + O_PRA);
    ushort_t* prB = (ushort_t*)(ws + O_PRB);
    u64* keysNN = (u64*)(ws + O_KNN);
    u64* keysRP = (u64*)(ws + O_KRP);
    float* partials = (float*)(ws + O_PART);

    k_prep<<<N_GT / 256, 256, 0, stream>>>(pred, gt, gtA, prA, prB);
    k_pair<<<ALL_WAVES / 4, 256, 0, stream>>>(gtA, prA, prB, keysNN, keysRP);
    k_fin<<<N_PRED / 4, 256, 0, stream>>>(pred, gt, keysNN, keysRP, partials);
    k_comb<<<1, 256, 0, stream>>>(partials, out);
}

// Round 14
// 35.659 us; speedup vs baseline: 1.1872x; 1.1102x over previous
//
#include <hip/hip_runtime.h>
#include <cstdint>

typedef unsigned short ushort_t;
typedef unsigned int u32;
typedef unsigned long long u64;
typedef __attribute__((ext_vector_type(8))) short bf16x8;
typedef __attribute__((ext_vector_type(16))) float f32x16;

#define N_PRED 8192
#define N_GT   32768

// block = 4 waves sharing one 512-target split; wave = 128 preds x 512 targets
// NN: 16 pgBase x 64 splits = 1024 blocks; REP: 16 pgBase x 16 splits = 256
#define NN_BLOCKS 1024
#define RP_BLOCKS 256

// ws: keysNN u64[64][8192] 4MB | keysRP u64[16][8192] 1MB | partials f32[2048][3]
#define O_KRP  4194304u
#define O_PART 5242880u

__device__ __forceinline__ float max3f(float a, float b, float c) {
    float d;
    asm("v_max3_f32 %0, %1, %2, %3" : "=v"(d) : "v"(a), "v"(b), "v"(c));
    return d;
}
__device__ __forceinline__ ushort_t f2b(float v) {   // round-to-nearest-even bf16
    u32 b = __float_as_uint(v);
    return (ushort_t)((b + 0x7FFFu + ((b >> 16) & 1u)) >> 16);
}
__device__ __forceinline__ float b2f(ushort_t h) {
    return __uint_as_float((u32)h << 16);
}
__device__ __forceinline__ u32 packf(float v) {      // monotone float->u32
    const u32 b = __float_as_uint(v);
    return b ^ ((u32)((int)b >> 31) | 0x80000000u);
}
// fold 16 accs into running max (8 x v_max3 + 1 fmax)
__device__ __forceinline__ float red16(const f32x16 a, float best) {
    const float m0 = max3f(a[0], a[1], a[2]);
    const float m1 = max3f(a[3], a[4], a[5]);
    const float m2 = max3f(a[6], a[7], a[8]);
    const float m3 = max3f(a[9], a[10], a[11]);
    const float m4 = max3f(a[12], a[13], a[14]);
    const float m5 = max3f(m0, m1, a[15]);
    const float m6 = max3f(m2, m3, m4);
    return max3f(best, m5, m6);
}

// mask the self element (C/D: col=lane&31, row=(r&3)+8*(r>>2)+4*(lane>>5))
#define MASKROW(ACC)                                               \
    {                                                              \
        _Pragma("unroll")                                          \
        for (int _r = 0; _r < 16; ++_r) {                          \
            const int _row = (_r & 3) + 8 * (_r >> 2) + rowoff;    \
            ACC[_r] = (_row == col) ? -3.0e38f : ACC[_r];          \
        }                                                          \
    }

// ---- scan: 16 A-tiles from LDS, lean body, argmax latched per 4-tile group ----
template <bool DIAG>
__device__ __forceinline__ void scan16(const bf16x8* __restrict__ ap,
                                       const bf16x8 B0, const bf16x8 B1,
                                       const bf16x8 B2, const bf16x8 B3,
                                       const int ts0, const int ts1,
                                       const int ts2, const int ts3,
                                       const int col, const int rowoff,
                                       float& b0, float& b1, float& b2, float& b3,
                                       u32& k0, u32& k1, u32& k2, u32& k3) {
    const f32x16 zc = {};
    bf16x8 Acur = ap[0];
#pragma unroll
    for (int G = 0; G < 4; ++G) {
        float g0 = -3.0e38f, g1 = -3.0e38f, g2 = -3.0e38f, g3 = -3.0e38f;
#pragma unroll
        for (int tt = 0; tt < 4; ++tt) {
            const int t = G * 4 + tt;
            const bf16x8 Anxt = (t < 15) ? ap[(t + 1) * 64] : Acur;
            f32x16 accA = __builtin_amdgcn_mfma_f32_32x32x16_bf16(Acur, B0, zc, 0, 0, 0);
            f32x16 accB = __builtin_amdgcn_mfma_f32_32x32x16_bf16(Acur, B1, zc, 0, 0, 0);
            if (DIAG && t == ts0) MASKROW(accA);
            g0 = red16(accA, g0);
            accA = __builtin_amdgcn_mfma_f32_32x32x16_bf16(Acur, B2, zc, 0, 0, 0);
            if (DIAG && t == ts1) MASKROW(accB);
            g1 = red16(accB, g1);
            accB = __builtin_amdgcn_mfma_f32_32x32x16_bf16(Acur, B3, zc, 0, 0, 0);
            if (DIAG && t == ts2) MASKROW(accA);
            g2 = red16(accA, g2);
            if (DIAG && t == ts3) MASKROW(accB);
            g3 = red16(accB, g3);
            Acur = Anxt;
        }
        k0 = (g0 > b0) ? (u32)G : k0;  b0 = fmaxf(b0, g0);
        k1 = (g1 > b1) ? (u32)G : k1;  b1 = fmaxf(b1, g1);
        k2 = (g2 > b2) ? (u32)G : k2;  b2 = fmaxf(b2, g2);
        k3 = (g3 > b3) ? (u32)G : k3;  b3 = fmaxf(b3, g3);
    }
}

// ---- fused pair: in-kernel fragment pack (A->LDS, B->regs) + MFMA argmax ----
// A (target): k0-7=[xh,yh,zh,xh,yh,zh,xl,yl]  k8-15=[zl,wh,wl,0...]  (w=-0.5|g|^2)
// B (query) : k0-7=[xh,yh,zh,xl,yl,zl,xh,yh]  k8-15=[zh,1,1,0...]
__global__ __launch_bounds__(256) void k_pair(const float* __restrict__ pred,
                                              const float* __restrict__ gt,
                                              u64* __restrict__ keysNN,
                                              u64* __restrict__ keysRP) {
    __shared__ bf16x8 As[1024];          // 16 tiles x 64 frags = 16 KB
    const int w = threadIdx.x >> 6;
    const int lane = threadIdx.x & 63;
    const int b = blockIdx.x;
    const bool isNN = (b < NN_BLOCKS);
    const int pgBase = isNN ? (b >> 6) : ((b - NN_BLOCKS) >> 4);
    const int sp     = isNN ? (b & 63) : ((b - NN_BLOCKS) & 15);
    const int pg = pgBase * 4 + w;

    // ---- stage the 512-target split into LDS (2 points/thread) ----
    const float* __restrict__ src = isNN ? gt : pred;
#pragma unroll
    for (int k = 0; k < 2; ++k) {
        const int idx = k * 256 + threadIdx.x;      // 0..511
        const int gidx = sp * 512 + idx;
        const float x = src[gidx * 6 + 0], y = src[gidx * 6 + 1], z = src[gidx * 6 + 2];
        const ushort_t xh = f2b(x), yh = f2b(y), zh = f2b(z);
        const ushort_t xl = f2b(x - b2f(xh));
        const ushort_t yl = f2b(y - b2f(yh));
        const ushort_t zl = f2b(z - b2f(zh));
        const float wv = -0.5f * fmaf(z, z, fmaf(y, y, x * x));
        const ushort_t wh = f2b(wv);
        const ushort_t wl = f2b(wv - b2f(wh));
        bf16x8 h0, h1;
        h0[0] = (short)xh; h0[1] = (short)yh; h0[2] = (short)zh; h0[3] = (short)xh;
        h0[4] = (short)yh; h0[5] = (short)zh; h0[6] = (short)xl; h0[7] = (short)yl;
        h1[0] = (short)zl; h1[1] = (short)wh; h1[2] = (short)wl; h1[3] = 0;
        h1[4] = 0; h1[5] = 0; h1[6] = 0; h1[7] = 0;
        const int t = idx >> 5, row_ = idx & 31;
        As[t * 64 + row_] = h0;
        As[t * 64 + 32 + row_] = h1;
    }

    // ---- B fragments from raw pred (4 per lane) ----
    const int col = lane & 31;
    const int kh = lane >> 5;
    const int rowoff = kh * 4;
    const ushort_t ONE = 0x3F80;
    bf16x8 B[4];
#pragma unroll
    for (int j = 0; j < 4; ++j) {
        const int p = pg * 128 + j * 32 + col;
        const float x = pred[p * 6 + 0], y = pred[p * 6 + 1], z = pred[p * 6 + 2];
        const ushort_t xh = f2b(x), yh = f2b(y), zh = f2b(z);
        const ushort_t xl = f2b(x - b2f(xh));
        const ushort_t yl = f2b(y - b2f(yh));
        const ushort_t zl = f2b(z - b2f(zh));
        B[j][0] = (short)(kh ? zh : xh);
        B[j][1] = (short)(kh ? ONE : yh);
        B[j][2] = (short)(kh ? ONE : zh);
        B[j][3] = (short)(kh ? 0 : xl);
        B[j][4] = (short)(kh ? 0 : yl);
        B[j][5] = (short)(kh ? 0 : zl);
        B[j][6] = (short)(kh ? 0 : xh);
        B[j][7] = (short)(kh ? 0 : yh);
    }
    __syncthreads();

    const bf16x8* ap = &As[lane];
    float b0 = -3.0e38f, b1 = -3.0e38f, b2 = -3.0e38f, b3 = -3.0e38f;
    u32 k0 = 0, k1 = 0, k2 = 0, k3 = 0;

    const bool diag = (!isNN) && (sp == pgBase);    // block-uniform
    if (diag) {
        const int tb = w * 4;                        // pg&3 == w
        scan16<true>(ap, B[0], B[1], B[2], B[3], tb, tb + 1, tb + 2, tb + 3,
                     col, rowoff, b0, b1, b2, b3, k0, k1, k2, k3);
    } else {
        scan16<false>(ap, B[0], B[1], B[2], B[3], -1, -1, -1, -1,
                      col, rowoff, b0, b1, b2, b3, k0, k1, k2, k3);
    }

    // merge row-halves (lane, lane^32 share a pred col); tie -> smaller group
#define FOLD(B_, K_)                                                \
    {                                                               \
        const float _ob = __shfl_xor(B_, 32);                       \
        const u32 _ok = __shfl_xor(K_, 32);                         \
        const bool _tk = (_ob > B_) || (_ob == B_ && _ok < K_);     \
        B_ = _tk ? _ob : B_;                                        \
        K_ = _tk ? _ok : K_;                                        \
    }
    FOLD(b0, k0); FOLD(b1, k1); FOLD(b2, k2); FOLD(b3, k3);
#undef FOLD

    if (lane < 32) {
        u64* keys = isNN ? keysNN : keysRP;
        const int Pb = pg * 128 + col;
        const u32 gb = (u32)(sp * 4);
        keys[(size_t)sp * N_PRED + Pb +  0] = ((u64)packf(b0) << 32) | (u64)(~(gb + k0));
        keys[(size_t)sp * N_PRED + Pb + 32] = ((u64)packf(b1) << 32) | (u64)(~(gb + k1));
        keys[(size_t)sp * N_PRED + Pb + 64] = ((u64)packf(b2) << 32) | (u64)(~(gb + k2));
        keys[(size_t)sp * N_PRED + Pb + 96] = ((u64)packf(b3) << 32) | (u64)(~(gb + k3));
    }
}

// ---- finalize: wave-per-pred; key reduce; 128-point exact rescans; losses ----
__global__ __launch_bounds__(256) void k_fin(const float* __restrict__ pred,
                                             const float* __restrict__ gt,
                                             const u64* __restrict__ keysNN,
                                             const u64* __restrict__ keysRP,
                                             float* __restrict__ partials) {
    const int wave = threadIdx.x >> 6;
    const int lane = threadIdx.x & 63;
    const int p = blockIdx.x * 4 + wave;

    const float px = pred[p * 6 + 0], py = pred[p * 6 + 1], pz = pred[p * 6 + 2];

    // --- NN: reduce 64 split keys (bigger h, then smaller group) ---
    u64 kv = keysNN[(size_t)lane * N_PRED + p];
#pragma unroll
    for (int off = 32; off > 0; off >>= 1) {
        const u64 o = __shfl_xor(kv, off);
        kv = (o > kv) ? o : kv;
    }
    const int G = (int)(~(u32)kv);          // group of 128 gt
    float bh = -3.0e38f;
    int bj = 0x7FFFFFFF;
#pragma unroll
    for (int i = 0; i < 2; ++i) {
        const int g = G * 128 + i * 64 + lane;
        const float x = gt[g * 6 + 0], y = gt[g * 6 + 1], z = gt[g * 6 + 2];
        const float w = -0.5f * fmaf(z, z, fmaf(y, y, x * x));
        const float h = fmaf(px, x, fmaf(py, y, fmaf(pz, z, w)));
        if (h > bh) { bh = h; bj = g; }
    }
#pragma unroll
    for (int off = 32; off > 0; off >>= 1) {
        const float oh = __shfl_xor(bh, off);
        const int og = __shfl_xor(bj, off);
        const bool take = (oh > bh) || (oh == bh && og < bj);
        bh = take ? oh : bh;
        bj = take ? og : bj;
    }
    const int j = bj;

    // --- REP: reduce 16 self-free split keys, exact 128-point rescan ---
    u64 rv = (lane < 16) ? keysRP[(size_t)lane * N_PRED + p] : 0ull;
#pragma unroll
    for (int off = 32; off > 0; off >>= 1) {
        const u64 o = __shfl_xor(rv, off);
        rv = (o > rv) ? o : rv;
    }
    const int G2 = (int)(~(u32)rv);         // group of 128 pred
    float hr = -3.0e38f;
#pragma unroll
    for (int i = 0; i < 2; ++i) {
        const int q = G2 * 128 + i * 64 + lane;
        const float x = pred[q * 6 + 0], y = pred[q * 6 + 1], z = pred[q * 6 + 2];
        const float w = -0.5f * fmaf(z, z, fmaf(y, y, x * x));
        float h = fmaf(px, x, fmaf(py, y, fmaf(pz, z, w)));
        h = (q == p) ? -3.0e38f : h;
        hr = fmaxf(hr, h);
    }
#pragma unroll
    for (int off = 32; off > 0; off >>= 1) hr = fmaxf(hr, __shfl_xor(hr, off));

    __shared__ float red[4][3];
    if (lane == 0) {
        const float gx = gt[j * 6 + 0], gy = gt[j * 6 + 1], gz = gt[j * 6 + 2];
        const float dx = px - gx, dy = py - gy, dz = pz - gz;
        const float att = dx * dx + dy * dy + dz * dz;

        const float pnx = pred[p * 6 + 3], pny = pred[p * 6 + 4], pnz = pred[p * 6 + 5];
        const float gnx = gt[j * 6 + 3],   gny = gt[j * 6 + 4],   gnz = gt[j * 6 + 5];
        const float pl = fmaxf(sqrtf(pnx * pnx + pny * pny + pnz * pnz), 1e-5f);
        const float gl = fmaxf(sqrtf(gnx * gnx + gny * gny + gnz * gnz), 1e-5f);
        const float nrm = 1.0f - (pnx * gnx + pny * gny + pnz * gnz) / (pl * gl);

        const float pp2 = px * px + py * py + pz * pz;
        float d2 = fmaf(-2.0f, hr, pp2);
        d2 = fmaxf(d2, 0.0f);
        const float xa = 100.0f * (0.3f - sqrtf(d2));
        const float sp2 = fmaxf(xa, 0.0f) + log1pf(expf(-fabsf(xa)));

        red[wave][0] = att;
        red[wave][1] = nrm;
        red[wave][2] = sp2 * sp2;
    }
    __syncthreads();
    if (threadIdx.x < 3)
        partials[blockIdx.x * 3 + threadIdx.x] =
            red[0][threadIdx.x] + red[1][threadIdx.x] +
            red[2][threadIdx.x] + red[3][threadIdx.x];
}

__device__ __forceinline__ float wave_reduce(float v) {
#pragma unroll
    for (int off = 32; off > 0; off >>= 1) v += __shfl_down(v, off, 64);
    return v;
}

__global__ __launch_bounds__(256) void k_comb(const float* __restrict__ partials,
                                              float* __restrict__ out) {
    float a = 0.f, n = 0.f, r = 0.f;
    const int t = threadIdx.x;
#pragma unroll
    for (int k = 0; k < 8; ++k) {
        const int row = t + k * 256;          // 2048 rows
        a += partials[row * 3 + 0];
        n += partials[row * 3 + 1];
        r += partials[row * 3 + 2];
    }
    a = wave_reduce(a);
    n = wave_reduce(n);
    r = wave_reduce(r);
    __shared__ float red[3][4];
    const int wave = t >> 6, lane = t & 63;
    if (lane == 0) { red[0][wave] = a; red[1][wave] = n; red[2][wave] = r; }
    __syncthreads();
    if (t == 0) {
        const float A = red[0][0] + red[0][1] + red[0][2] + red[0][3];
        const float Nn = red[1][0] + red[1][1] + red[1][2] + red[1][3];
        const float R = red[2][0] + red[2][1] + red[2][2] + red[2][3];
        out[0] = A / (float)(N_PRED * 3) + R / (float)N_PRED + 10.0f * (Nn / (float)N_PRED);
    }
}

extern "C" void kernel_launch(void* const* d_in, const int* in_sizes, int n_in,
                              void* d_out, int out_size, void* d_ws, size_t ws_size,
                              hipStream_t stream) {
    const float* pred = (const float*)d_in[0];   // (8192, 6)
    const float* gt   = (const float*)d_in[3];   // (32768, 6)
    float* out = (float*)d_out;
    char* ws = (char*)d_ws;

    u64* keysNN = (u64*)ws;
    u64* keysRP = (u64*)(ws + O_KRP);
    float* partials = (float*)(ws + O_PART);

    k_pair<<<NN_BLOCKS + RP_BLOCKS, 256, 0, stream>>>(pred, gt, keysNN, keysRP);
    k_fin<<<N_PRED / 4, 256, 0, stream>>>(pred, gt, keysNN, keysRP, partials);
    k_comb<<<1, 256, 0, stream>>>(partials, out);
}